// Round 7
// baseline (303.410 us; speedup 1.0000x reference)
//
#include <hip/hip_runtime.h>

#define IN_C 128
#define HID_C 128
#define OUT_C 64

#define BSPAN 256        // dst nodes per bucket
#define BCAP  5120       // edge capacity per bucket (mean 4096 + 16 sigma)
#define NBMAX 512        // max buckets (requires N <= 131072 for 17-bit src pack)
#define ACHUNK 4096      // edges per bin_edges block

typedef unsigned int uint32;
typedef unsigned short ushort16;
typedef _Float16 f16;
typedef f16   f16x8 __attribute__((ext_vector_type(8)));
typedef float f32x4 __attribute__((ext_vector_type(4)));

// ---------------- bf16 helpers ----------------

__device__ __forceinline__ ushort16 f2bf(float f) {
    union { float f; uint32 u; } v; v.f = f;
    uint32 r = v.u + 0x7FFFu + ((v.u >> 16) & 1u);   // round-to-nearest-even
    return (ushort16)(r >> 16);
}

__device__ __forceinline__ void unpack2(uint32 u, float& f0, float& f1) {
    union { uint32 x; float f; } a, b;
    a.x = u << 16;
    b.x = u & 0xFFFF0000u;
    f0 = a.f; f1 = b.f;
}

__device__ __forceinline__ void acc_row(uint4 r, float* acc) {
    float f0, f1;
    unpack2(r.x, f0, f1); acc[0] += f0; acc[1] += f1;
    unpack2(r.y, f0, f1); acc[2] += f0; acc[3] += f1;
    unpack2(r.z, f0, f1); acc[4] += f0; acc[5] += f1;
    unpack2(r.w, f0, f1); acc[6] += f0; acc[7] += f1;
}

// ---------------- phase A: bin edges by dst bucket ----------------
// NOTE (R5): do NOT add per-node degree atomics here — 1.6M random global
// atomics cost ~55 us (bin_edges 22 -> 77 us, latency-serialized).

__launch_bounds__(256)
__global__ void bin_edges_kernel(const int* __restrict__ src, const int* __restrict__ dst,
                                 int* __restrict__ bucketCur, uint32* __restrict__ binned,
                                 int E, int nbuck) {
    __shared__ int hist[NBMAX];
    __shared__ int base[NBMAX];
    const int tid = threadIdx.x;
    const int e0  = blockIdx.x * ACHUNK;

    for (int i = tid; i < NBMAX; i += 256) hist[i] = 0;
    __syncthreads();

    int d[16], s[16], rk[16];
#pragma unroll
    for (int j = 0; j < 16; j++) {
        int e = e0 + j * 256 + tid;
        if (e < E) {
            d[j] = dst[e];
            s[j] = src[e];
            rk[j] = atomicAdd(&hist[d[j] >> 8], 1);
        } else d[j] = -1;
    }
    __syncthreads();

    for (int b = tid; b < nbuck; b += 256) {
        int h = hist[b];
        base[b] = h ? atomicAdd(&bucketCur[b], h) : 0;
    }
    __syncthreads();

#pragma unroll
    for (int j = 0; j < 16; j++) {
        if (d[j] >= 0) {
            int b = d[j] >> 8;
            int pos = base[b] + rk[j];
            if (pos < BCAP)
                binned[(size_t)b * BCAP + pos] =
                    ((uint32)(d[j] & 255) << 17) | (uint32)s[j];
        }
    }
}

// ---------------- phase B: per-bucket CSR + degree + inv ----------------

__launch_bounds__(256)
__global__ void bucket_csr_kernel(const uint32* __restrict__ binned,
                                  const int* __restrict__ bucketCur,
                                  int* __restrict__ csr_src, int* __restrict__ rowbeg,
                                  int* __restrict__ rowend, float* __restrict__ inv, int N) {
    constexpr int MAXIT = BCAP / 256;   // 20
    __shared__ int cnt[BSPAN];
    __shared__ int scn[BSPAN];
    __shared__ int excl[BSPAN];
    const int b   = blockIdx.x;
    const int tid = threadIdx.x;
    const int n0  = b * BSPAN;
    const int ne  = min(bucketCur[b], BCAP);
    const uint32* bp = binned + (size_t)b * BCAP;

    cnt[tid] = 0;
    __syncthreads();

    uint32 ebuf[MAXIT];
    int    rbuf[MAXIT];
    int nmine = 0;
    for (int i = tid; i < ne; i += 256) {
        uint32 e = bp[i];
        ebuf[nmine] = e;
        rbuf[nmine] = atomicAdd(&cnt[e >> 17], 1);
        nmine++;
    }
    __syncthreads();

    int v = cnt[tid];
    scn[tid] = v;
    __syncthreads();
    for (int off = 1; off < 256; off <<= 1) {
        int u = (tid >= off) ? scn[tid - off] : 0;
        __syncthreads();
        scn[tid] += u;
        __syncthreads();
    }
    int ex = scn[tid] - v;
    excl[tid] = ex;

    int n = n0 + tid;
    if (n < N) {
        int gb = b * BCAP + ex;
        rowbeg[n] = gb;
        rowend[n] = gb + v;
        inv[n] = rsqrtf((float)(v + 1));   // +1 self-loop
    }
    __syncthreads();

    for (int j = 0; j < nmine; j++) {
        uint32 e = ebuf[j];
        csr_src[(size_t)b * BCAP + excl[e >> 17] + rbuf[j]] = (int)(e & 0x1FFFFu);
    }
}

// ---------------- W -> MFMA B-fragment layout (fp16) + bucketCur zeroing ----------------

template <int C>
__device__ __forceinline__ void wprep_one(const float* __restrict__ W, f16* __restrict__ Wf, int t) {
    constexpr int NCT = C / 16;
    int lane = t & 63;
    int ctkc = t >> 6;
    int ct = ctkc % NCT, kc = ctkc / NCT;
    int kbase = kc * 32 + (lane >> 4) * 8;
    int col   = ct * 16 + (lane & 15);
    f16 v[8];
#pragma unroll
    for (int j = 0; j < 8; j++) v[j] = (f16)W[(size_t)(kbase + j) * C + col];
    *(uint4*)(Wf + (size_t)t * 8) = *(const uint4*)v;
}

__global__ void wprep_both(const float* __restrict__ W1, f16* __restrict__ Wf1,
                           const float* __restrict__ W2, f16* __restrict__ Wf2,
                           int* __restrict__ bucketCur, int nbuck) {
    constexpr int T1 = 4 * (HID_C / 16) * 64;   // 2048
    constexpr int T2 = 4 * (OUT_C / 16) * 64;   // 1024
    int t = blockIdx.x * 256 + threadIdx.x;
    if (t < nbuck) bucketCur[t] = 0;
    if (t < T1)            wprep_one<HID_C>(W1, Wf1, t);
    else if (t < T1 + T2)  wprep_one<OUT_C>(W2, Wf2, t - T1);
}

// ---------------- MFMA GEMM (layer 1): row-major bf16 out ----------------

template <int C>
__launch_bounds__(256)
__global__ void mfma_gemm(const float* __restrict__ X, const f16* __restrict__ Wf,
                          const float* __restrict__ inv, ushort16* __restrict__ outb, int N) {
    constexpr int NCT = C / 16;
    __shared__ __align__(16) f16 As[4 * 4 * 64 * 8];        // 16 KB: [kc][w][lane][8]
    __shared__ __align__(16) f16 Bs[4 * NCT * 64 * 8];      // 32 KB (C=128)

    const int tid  = threadIdx.x;
    const int lane = tid & 63;
    const int w    = tid >> 6;
    const int row0 = blockIdx.x * 64;

    // ---- stage Wf -> Bs ----
    {
        constexpr int TOT = 4 * NCT * 64 * 8;
        const uint4* src = (const uint4*)Wf;
        uint4* dst = (uint4*)Bs;
#pragma unroll
        for (int i = 0; i < TOT / 8 / 256; i++)
            dst[tid + i * 256] = src[tid + i * 256];
    }

    // ---- stage X tile -> As (fragment-major) ----
    {
        int r   = tid >> 2;            // tile row 0..63
        int seg = tid & 3;             // k chunk (kc)
        int row = row0 + r;
        int ws_ = r >> 4;
        int r15 = r & 15;
#pragma unroll
        for (int i = 0; i < 8; i++) {
            int k = seg * 32 + i * 4;
            float4 v = make_float4(0.f, 0.f, 0.f, 0.f);
            if (row < N) v = *(const float4*)(X + (size_t)row * 128 + k);
            int q = (k >> 3) & 3, j0 = k & 7;
            f16 h[4] = {(f16)v.x, (f16)v.y, (f16)v.z, (f16)v.w};
            int slot = ((seg * 4 + ws_) * 64 + (q * 16 + r15)) * 8 + j0;
            *(uint2*)(As + slot) = *(const uint2*)h;
        }
    }
    __syncthreads();

    // ---- MFMA ----
    f32x4 acc[NCT];
#pragma unroll
    for (int c = 0; c < NCT; c++) acc[c] = (f32x4){0.f, 0.f, 0.f, 0.f};
#pragma unroll
    for (int kc = 0; kc < 4; kc++) {
        f16x8 a = *(const f16x8*)&As[((kc * 4 + w) * 64 + lane) * 8];
#pragma unroll
        for (int ct = 0; ct < NCT; ct++) {
            f16x8 b = *(const f16x8*)&Bs[((kc * NCT + ct) * 64 + lane) * 8];
            acc[ct] = __builtin_amdgcn_mfma_f32_16x16x32_f16(a, b, acc[ct], 0, 0, 0);
        }
    }

    // ---- epilogue via LDS bounce ----
    __syncthreads();
    ushort16* Ds = (ushort16*)As;      // [64][C]
    const int q = lane >> 4;
    float iv[4];
#pragma unroll
    for (int reg = 0; reg < 4; reg++) {
        int row = row0 + w * 16 + q * 4 + reg;
        iv[reg] = (row < N) ? inv[row] : 0.f;
    }
#pragma unroll
    for (int ct = 0; ct < NCT; ct++) {
#pragma unroll
        for (int reg = 0; reg < 4; reg++) {
            int r = w * 16 + q * 4 + reg;
            Ds[r * C + ct * 16 + (lane & 15)] = f2bf(acc[ct][reg] * iv[reg]);
        }
    }
    __syncthreads();
    {
        int r  = tid >> 2;
        int row = row0 + r;
        if (row < N) {
            constexpr int SPT = C / 4;
            int c0 = (tid & 3) * SPT;
            const uint4* s = (const uint4*)&Ds[r * C + c0];
            uint4* d = (uint4*)(outb + (size_t)row * C + c0);
#pragma unroll
            for (int i = 0; i < SPT / 8; i++) d[i] = s[i];
        }
    }
}

// ---------------- FUSED: gather-agg layer 1 (relu) -> LDS A-fragments -> GEMM2 ----------------
// Gather + MFMA identical to the proven 69us/48-VGPR R2 structure. ONLY the
// epilogue changed (R6): hs2 is written SLICE-MAJOR f16 [4][N][16ch] so the
// layer-2 gather can be XCD-sliced (each slice 3.2MB -> L2-resident).

__launch_bounds__(512, 4)
__global__ void fused_gather_gemm(const int* __restrict__ rowbeg, const int* __restrict__ rowend,
                                  const int* __restrict__ csr,
                                  const ushort16* __restrict__ hsb,    // [N][128] bf16
                                  const float* __restrict__ inv, const float* __restrict__ bias1,
                                  const f16* __restrict__ Wf2,         // B-frag, K=128, C=64
                                  f16* __restrict__ hs2s, int N) {     // [4][N][16] f16 slice-major
    constexpr int CIN = 128, COUT = 64, NCT = COUT / 16;    // NCT=4
    __shared__ __align__(16) f16 As[4 * 4 * 64 * 8];        // 16 KB
    __shared__ __align__(16) f16 Bs[4 * NCT * 64 * 8];      // 16 KB

    const int tid  = threadIdx.x;
    const int lane = tid & 63;
    const int w    = tid >> 6;          // 0..7
    const int row0 = blockIdx.x * 64;

    // ---- stage Wf2 -> Bs (1024 uint4, 512 threads x 2) ----
    {
        const uint4* s = (const uint4*)Wf2;
        uint4* d = (uint4*)Bs;
        d[tid]       = s[tid];
        d[tid + 512] = s[tid + 512];
    }

    // ---- gather phase (channel-split eighths; R2-proven) ----
    {
        const int r = tid >> 3;         // node 0..63
        const int q = tid & 7;          // channel eighth
        const int n = row0 + r;
        float acc[16];
#pragma unroll
        for (int j = 0; j < 16; j++) acc[j] = 0.f;

        if (n < N) {
            {   // self-loop row
                const ushort16* base = hsb + (size_t)n * CIN + q * 16;
                uint4 s0 = *(const uint4*)(base);
                uint4 s1 = *(const uint4*)(base + 8);
                acc_row(s0, acc); acc_row(s1, acc + 8);
            }
            const int end = rowend[n];
            int i = rowbeg[n];
            for (; i + 4 <= end; i += 4) {    // 4-edge unroll -> 8 outstanding 16B loads
                const ushort16* p0 = hsb + (size_t)csr[i]     * CIN + q * 16;
                const ushort16* p1 = hsb + (size_t)csr[i + 1] * CIN + q * 16;
                const ushort16* p2 = hsb + (size_t)csr[i + 2] * CIN + q * 16;
                const ushort16* p3 = hsb + (size_t)csr[i + 3] * CIN + q * 16;
                uint4 a0 = *(const uint4*)(p0);
                uint4 a1 = *(const uint4*)(p0 + 8);
                uint4 b0 = *(const uint4*)(p1);
                uint4 b1 = *(const uint4*)(p1 + 8);
                uint4 c0 = *(const uint4*)(p2);
                uint4 c1 = *(const uint4*)(p2 + 8);
                uint4 d0 = *(const uint4*)(p3);
                uint4 d1 = *(const uint4*)(p3 + 8);
                acc_row(a0, acc); acc_row(a1, acc + 8);
                acc_row(b0, acc); acc_row(b1, acc + 8);
                acc_row(c0, acc); acc_row(c1, acc + 8);
                acc_row(d0, acc); acc_row(d1, acc + 8);
            }
            for (; i < end; i++) {
                const ushort16* p0 = hsb + (size_t)csr[i] * CIN + q * 16;
                uint4 a0 = *(const uint4*)(p0);
                uint4 a1 = *(const uint4*)(p0 + 8);
                acc_row(a0, acc); acc_row(a1, acc + 8);
            }

            float iv = inv[n];
#pragma unroll
            for (int j = 0; j < 16; j++)
                acc[j] = fmaxf(fmaf(iv, acc[j], bias1[q * 16 + j]), 0.f);
        }

        // write h1 (f16) into As in A-fragment layout: channel k = q*16 + u*8 + j
        const int ws_ = r >> 4, r15 = r & 15;
        const int seg = q >> 1;
#pragma unroll
        for (int u = 0; u < 2; u++) {
            const int i8 = (q & 1) * 2 + u;
            f16 hv[8];
#pragma unroll
            for (int j = 0; j < 8; j++) hv[j] = (f16)acc[u * 8 + j];
            int slot = ((seg * 4 + ws_) * 64 + (i8 * 16 + r15)) * 8;
            *(uint4*)(As + slot) = *(const uint4*)hv;
        }
    }
    __syncthreads();

    // ---- MFMA: hs2 = inv * (h1 @ W2), waves 0-3 only ----
    f32x4 acc2[NCT];
#pragma unroll
    for (int c = 0; c < NCT; c++) acc2[c] = (f32x4){0.f, 0.f, 0.f, 0.f};
    if (w < 4) {
#pragma unroll
        for (int kc = 0; kc < 4; kc++) {
            f16x8 a = *(const f16x8*)&As[((kc * 4 + w) * 64 + lane) * 8];
#pragma unroll
            for (int ct = 0; ct < NCT; ct++) {
                f16x8 b = *(const f16x8*)&Bs[((kc * NCT + ct) * 64 + lane) * 8];
                acc2[ct] = __builtin_amdgcn_mfma_f32_16x16x32_f16(a, b, acc2[ct], 0, 0, 0);
            }
        }
    }

    // ---- epilogue via LDS bounce (reuse As), f16, slice-major store ----
    __syncthreads();
    f16* Ds = (f16*)As;                // [64][COUT] f16
    if (w < 4) {
        const int q2 = lane >> 4;
        float iv2[4];
#pragma unroll
        for (int reg = 0; reg < 4; reg++) {
            int row = row0 + w * 16 + q2 * 4 + reg;
            iv2[reg] = (row < N) ? inv[row] : 0.f;
        }
#pragma unroll
        for (int ct = 0; ct < NCT; ct++) {
#pragma unroll
            for (int reg = 0; reg < 4; reg++) {
                int r = w * 16 + q2 * 4 + reg;
                Ds[r * COUT + ct * 16 + (lane & 15)] = (f16)(acc2[ct][reg] * iv2[reg]);
            }
        }
    }
    __syncthreads();
    {
        const int r   = tid >> 3;          // 64 rows x 8 threads
        const int row = row0 + r;
        if (row < N) {
            const int c = tid & 7;         // 8ch = 16B chunk
            const int s = c >> 1, h = c & 1;
            uint4 v = *(const uint4*)&Ds[r * COUT + c * 8];
            *(uint4*)(hs2s + ((size_t)s * N + row) * 16 + h * 8) = v;
        }
    }
}

// ---------------- final gather (layer 2): XCD-SLICED ----------------
// hs2s is [4][N][16ch] f16 slice-major; slice footprint = N*32B = 3.2MB, fits
// one XCD's 4MB L2. slice = blockIdx%4: blocks land on XCD = blockIdx%8, so
// XCD x only ever touches slice x%4 -> random gather becomes L2-resident.
// 1 thread per node per slice; 4-edge unroll = 8 outstanding 16B loads.

__launch_bounds__(256)
__global__ void slice_gather2(const int* __restrict__ rowbeg, const int* __restrict__ rowend,
                              const int* __restrict__ csr_src,
                              const f16* __restrict__ hs2s,    // [4][N][16] f16
                              const float* __restrict__ inv, const float* __restrict__ b,
                              float* __restrict__ out, int N) {
    const int s = blockIdx.x & 3;
    const int n = (blockIdx.x >> 2) * 256 + threadIdx.x;
    if (n >= N) return;
    const f16* base = hs2s + (size_t)s * N * 16;

    float acc[16];
    {   // self row (inv-folded at GEMM2 time, same semantics as before)
        const f16x8* p = (const f16x8*)(base + (size_t)n * 16);
        f16x8 a0 = p[0], a1 = p[1];
#pragma unroll
        for (int j = 0; j < 8; j++) { acc[j] = (float)a0[j]; acc[8 + j] = (float)a1[j]; }
    }

    const int end = rowend[n];
    int i = rowbeg[n];
    for (; i + 4 <= end; i += 4) {       // 4-edge unroll -> 8 outstanding 16B loads
        const f16x8* p0 = (const f16x8*)(base + (size_t)csr_src[i]     * 16);
        const f16x8* p1 = (const f16x8*)(base + (size_t)csr_src[i + 1] * 16);
        const f16x8* p2 = (const f16x8*)(base + (size_t)csr_src[i + 2] * 16);
        const f16x8* p3 = (const f16x8*)(base + (size_t)csr_src[i + 3] * 16);
        f16x8 a0 = p0[0], a1 = p0[1];
        f16x8 b0 = p1[0], b1 = p1[1];
        f16x8 c0 = p2[0], c1 = p2[1];
        f16x8 d0 = p3[0], d1 = p3[1];
#pragma unroll
        for (int j = 0; j < 8; j++) {
            acc[j]     += (float)a0[j] + (float)b0[j] + (float)c0[j] + (float)d0[j];
            acc[8 + j] += (float)a1[j] + (float)b1[j] + (float)c1[j] + (float)d1[j];
        }
    }
    for (; i < end; i++) {
        const f16x8* p0 = (const f16x8*)(base + (size_t)csr_src[i] * 16);
        f16x8 a0 = p0[0], a1 = p0[1];
#pragma unroll
        for (int j = 0; j < 8; j++) { acc[j] += (float)a0[j]; acc[8 + j] += (float)a1[j]; }
    }

    const float iv = inv[n];
    const float* bp = b + s * 16;
    float* po = out + (size_t)n * 64 + s * 16;
#pragma unroll
    for (int j = 0; j < 16; j++) acc[j] = fmaf(iv, acc[j], bp[j]);
#pragma unroll
    for (int u = 0; u < 4; u++)
        *(float4*)(po + u * 4) = make_float4(acc[u * 4], acc[u * 4 + 1],
                                             acc[u * 4 + 2], acc[u * 4 + 3]);
}

extern "C" void kernel_launch(void* const* d_in, const int* in_sizes, int n_in,
                              void* d_out, int out_size, void* d_ws, size_t ws_size,
                              hipStream_t stream) {
    const float* x  = (const float*)d_in[0];
    const int*   ei = (const int*)d_in[1];
    const float* W1 = (const float*)d_in[2];
    const float* b1 = (const float*)d_in[3];
    const float* W2 = (const float*)d_in[4];
    const float* b2 = (const float*)d_in[5];
    float* out = (float*)d_out;

    const int N = in_sizes[0] / IN_C;    // 100000 (<= 131072 for src packing)
    const int E = in_sizes[1] / 2;       // 1600000
    const int* src = ei;
    const int* dst = ei + E;
    const int nbuck = (N + BSPAN - 1) / BSPAN;   // 391

    // workspace layout
    char* ws = (char*)d_ws;
    auto align_up = [](size_t v) { return (v + 1023) & ~(size_t)1023; };
    size_t off = 0;
    int*      bucketCur = (int*)(ws + off);      off += align_up((size_t)nbuck * sizeof(int));
    float*    inv       = (float*)(ws + off);    off += align_up((size_t)N * sizeof(float));
    int*      rowbeg    = (int*)(ws + off);      off += align_up((size_t)N * sizeof(int));
    int*      rowend    = (int*)(ws + off);      off += align_up((size_t)N * sizeof(int));
    uint32*   binned    = (uint32*)(ws + off);   off += align_up((size_t)nbuck * BCAP * sizeof(uint32));
    int*      csrs      = (int*)(ws + off);      off += align_up((size_t)nbuck * BCAP * sizeof(int));
    f16*      Wf1       = (f16*)(ws + off);      off += align_up((size_t)4 * (HID_C/16) * 64 * 8 * sizeof(f16));
    f16*      Wf2       = (f16*)(ws + off);      off += align_up((size_t)4 * (OUT_C/16) * 64 * 8 * sizeof(f16));
    ushort16* hs1b      = (ushort16*)(ws + off); off += align_up((size_t)N * HID_C * sizeof(ushort16));
    f16*      hs2s      = (f16*)(ws + off);      off += align_up((size_t)4 * N * 16 * sizeof(f16));

    // ---- preamble: weight swizzle (+bucketCur zero) -> binning -> CSR ----
    wprep_both<<<(4 * (HID_C/16 + OUT_C/16) * 64 + 255) / 256, 256, 0, stream>>>(
        W1, Wf1, W2, Wf2, bucketCur, nbuck);
    bin_edges_kernel<<<(E + ACHUNK - 1) / ACHUNK, 256, 0, stream>>>(
        src, dst, bucketCur, binned, E, nbuck);
    bucket_csr_kernel<<<nbuck, 256, 0, stream>>>(
        binned, bucketCur, csrs, rowbeg, rowend, inv, N);

    // ---- layer 1 GEMM ----
    mfma_gemm<HID_C><<<(N + 63) / 64, 256, 0, stream>>>(x, Wf1, inv, hs1b, N);

    // ---- fused: gather1 + relu + GEMM2 (hs2 written slice-major f16) ----
    fused_gather_gemm<<<(N + 63) / 64, 512, 0, stream>>>(
        rowbeg, rowend, csrs, hs1b, inv, b1, Wf2, hs2s, N);

    // ---- final gather: XCD-sliced (4 slices x 16ch) ----
    slice_gather2<<<((N + 255) / 256) * 4, 256, 0, stream>>>(
        rowbeg, rowend, csrs, hs2s, inv, b2, out, N);
}

// Round 8
// 257.821 us; speedup vs baseline: 1.1768x; 1.1768x over previous
//
#include <hip/hip_runtime.h>

#define IN_C 128
#define HID_C 128
#define OUT_C 64

#define BSPAN 256        // dst nodes per bucket
#define BCAP  5120       // edge capacity per bucket (mean 4096 + 16 sigma)
#define NBMAX 512        // max buckets (requires N <= 131072 for 17-bit src pack)
#define ACHUNK 4096      // edges per bin_edges block

typedef unsigned int uint32;
typedef unsigned short ushort16;
typedef _Float16 f16;
typedef f16   f16x8 __attribute__((ext_vector_type(8)));
typedef float f32x4 __attribute__((ext_vector_type(4)));

// ---------------- bf16 helpers ----------------

__device__ __forceinline__ ushort16 f2bf(float f) {
    union { float f; uint32 u; } v; v.f = f;
    uint32 r = v.u + 0x7FFFu + ((v.u >> 16) & 1u);   // round-to-nearest-even
    return (ushort16)(r >> 16);
}

__device__ __forceinline__ void unpack2(uint32 u, float& f0, float& f1) {
    union { uint32 x; float f; } a, b;
    a.x = u << 16;
    b.x = u & 0xFFFF0000u;
    f0 = a.f; f1 = b.f;
}

__device__ __forceinline__ void acc_row(uint4 r, float* acc) {
    float f0, f1;
    unpack2(r.x, f0, f1); acc[0] += f0; acc[1] += f1;
    unpack2(r.y, f0, f1); acc[2] += f0; acc[3] += f1;
    unpack2(r.z, f0, f1); acc[4] += f0; acc[5] += f1;
    unpack2(r.w, f0, f1); acc[6] += f0; acc[7] += f1;
}

// ---------------- W -> MFMA B-fragment helper ----------------

template <int C>
__device__ __forceinline__ void wprep_one(const float* __restrict__ W, f16* __restrict__ Wf, int t) {
    constexpr int NCT = C / 16;
    int lane = t & 63;
    int ctkc = t >> 6;
    int ct = ctkc % NCT, kc = ctkc / NCT;
    int kbase = kc * 32 + (lane >> 4) * 8;
    int col   = ct * 16 + (lane & 15);
    f16 v[8];
#pragma unroll
    for (int j = 0; j < 8; j++) v[j] = (f16)W[(size_t)(kbase + j) * C + col];
    *(uint4*)(Wf + (size_t)t * 8) = *(const uint4*)v;
}

// ---------------- MERGED phase A: bin edges (blocks < nbins) || weight prep ----------------
// bucketCur is zeroed by hipMemsetAsync before this dispatch.
// NOTE (R5): no per-node degree atomics here — 1.6M random global atomics
// cost ~55us. Per-node degree comes from deg_inv_kernel (bucket recount).

__launch_bounds__(256)
__global__ void bin_edges_wprep(const int* __restrict__ src, const int* __restrict__ dst,
                                int* __restrict__ bucketCur, uint32* __restrict__ binned,
                                const float* __restrict__ W1, f16* __restrict__ Wf1,
                                const float* __restrict__ W2, f16* __restrict__ Wf2,
                                int E, int nbins) {
    __shared__ int hist[NBMAX];
    __shared__ int base[NBMAX];
    const int tid = threadIdx.x;

    if ((int)blockIdx.x >= nbins) {
        // ---- weight prep branch ----
        constexpr int T1 = 4 * (HID_C / 16) * 64;   // 2048
        constexpr int T2 = 4 * (OUT_C / 16) * 64;   // 1024
        int t = ((int)blockIdx.x - nbins) * 256 + tid;
        if (t < T1)            wprep_one<HID_C>(W1, Wf1, t);
        else if (t < T1 + T2)  wprep_one<OUT_C>(W2, Wf2, t - T1);
        return;
    }

    const int e0 = blockIdx.x * ACHUNK;

    for (int i = tid; i < NBMAX; i += 256) hist[i] = 0;
    __syncthreads();

    int d[16], s[16], rk[16];
#pragma unroll
    for (int j = 0; j < 16; j++) {
        int e = e0 + j * 256 + tid;
        if (e < E) {
            d[j] = dst[e];
            s[j] = src[e];
            rk[j] = atomicAdd(&hist[d[j] >> 8], 1);
        } else d[j] = -1;
    }
    __syncthreads();

    for (int b = tid; b < NBMAX; b += 256) {
        int h = hist[b];
        base[b] = h ? atomicAdd(&bucketCur[b], h) : 0;
    }
    __syncthreads();

#pragma unroll
    for (int j = 0; j < 16; j++) {
        if (d[j] >= 0) {
            int b = d[j] >> 8;
            int pos = base[b] + rk[j];
            if (pos < BCAP)
                binned[(size_t)b * BCAP + pos] =
                    ((uint32)(d[j] & 255) << 17) | (uint32)s[j];
        }
    }
}

// ---------------- deg/inv from binned buckets (no global atomics) ----------------
// Block b recounts its bucket's packed entries (8-bit local dst) in LDS and
// writes inv for its 256 nodes. ~8MB sequential read total, ~5us.

__launch_bounds__(256)
__global__ void deg_inv_kernel(const uint32* __restrict__ binned,
                               const int* __restrict__ bucketCur,
                               float* __restrict__ inv, int N) {
    __shared__ int cnt[BSPAN];
    const int b   = blockIdx.x;
    const int tid = threadIdx.x;
    const int ne  = min(bucketCur[b], BCAP);
    const uint32* bp = binned + (size_t)b * BCAP;

    cnt[tid] = 0;
    __syncthreads();
    for (int i = tid; i < ne; i += 256)
        atomicAdd(&cnt[bp[i] >> 17], 1);
    __syncthreads();

    int n = b * BSPAN + tid;
    if (n < N) inv[n] = rsqrtf((float)(cnt[tid] + 1));   // +1 self-loop
}

// ---------------- MERGED: bucket CSR (blocks 0..ncsr-1) || layer-1 MFMA GEMM ----------------
// inv is precomputed by deg_inv_kernel, so the latency-bound csr blocks (391,
// ~1.5/CU) co-run with the BW-bound gemm blocks (1563) in one dispatch.

__launch_bounds__(256)
__global__ void csr_and_gemm(const uint32* __restrict__ binned, const int* __restrict__ bucketCur,
                             int* __restrict__ csr_src, int* __restrict__ rowbeg,
                             int* __restrict__ rowend,
                             const float* __restrict__ X, const f16* __restrict__ Wf,
                             const float* __restrict__ inv, ushort16* __restrict__ outb,
                             int N, int ncsr) {
    __shared__ __align__(16) char smem[49152];   // union: csr 3 KB | gemm 48 KB
    const int tid = threadIdx.x;

    if ((int)blockIdx.x < ncsr) {
        // ================= bucket CSR =================
        constexpr int MAXIT = BCAP / 256;   // 20
        int* cnt  = (int*)smem;             // [BSPAN]
        int* scn  = cnt + BSPAN;
        int* excl = scn + BSPAN;
        const int b   = blockIdx.x;
        const int n0  = b * BSPAN;
        const int ne  = min(bucketCur[b], BCAP);
        const uint32* bp = binned + (size_t)b * BCAP;

        cnt[tid] = 0;
        __syncthreads();

        uint32 ebuf[MAXIT];
        int    rbuf[MAXIT];
        int nmine = 0;
        for (int i = tid; i < ne; i += 256) {
            uint32 e = bp[i];
            ebuf[nmine] = e;
            rbuf[nmine] = atomicAdd(&cnt[e >> 17], 1);
            nmine++;
        }
        __syncthreads();

        int v = cnt[tid];
        scn[tid] = v;
        __syncthreads();
        for (int off = 1; off < 256; off <<= 1) {
            int u = (tid >= off) ? scn[tid - off] : 0;
            __syncthreads();
            scn[tid] += u;
            __syncthreads();
        }
        int ex = scn[tid] - v;
        excl[tid] = ex;

        int n = n0 + tid;
        if (n < N) {
            int gb = b * BCAP + ex;
            rowbeg[n] = gb;
            rowend[n] = gb + v;
        }
        __syncthreads();

        for (int j = 0; j < nmine; j++) {
            uint32 e = ebuf[j];
            csr_src[(size_t)b * BCAP + excl[e >> 17] + rbuf[j]] = (int)(e & 0x1FFFFu);
        }
    } else {
        // ================= layer-1 MFMA GEMM =================
        constexpr int C = HID_C;
        constexpr int NCT = C / 16;
        f16* As = (f16*)smem;                        // 16 KB
        f16* Bs = (f16*)(smem + 16384);              // 32 KB

        const int lane = tid & 63;
        const int w    = tid >> 6;
        const int row0 = ((int)blockIdx.x - ncsr) * 64;

        // ---- stage Wf -> Bs ----
        {
            constexpr int TOT = 4 * NCT * 64 * 8;
            const uint4* s = (const uint4*)Wf;
            uint4* d = (uint4*)Bs;
#pragma unroll
            for (int i = 0; i < TOT / 8 / 256; i++)
                d[tid + i * 256] = s[tid + i * 256];
        }

        // ---- stage X tile -> As (fragment-major) ----
        {
            int r   = tid >> 2;            // tile row 0..63
            int seg = tid & 3;             // k chunk (kc)
            int row = row0 + r;
            int ws_ = r >> 4;
            int r15 = r & 15;
#pragma unroll
            for (int i = 0; i < 8; i++) {
                int k = seg * 32 + i * 4;
                float4 v = make_float4(0.f, 0.f, 0.f, 0.f);
                if (row < N) v = *(const float4*)(X + (size_t)row * 128 + k);
                int q = (k >> 3) & 3, j0 = k & 7;
                f16 h[4] = {(f16)v.x, (f16)v.y, (f16)v.z, (f16)v.w};
                int slot = ((seg * 4 + ws_) * 64 + (q * 16 + r15)) * 8 + j0;
                *(uint2*)(As + slot) = *(const uint2*)h;
            }
        }
        __syncthreads();

        // ---- MFMA ----
        f32x4 acc[NCT];
#pragma unroll
        for (int c = 0; c < NCT; c++) acc[c] = (f32x4){0.f, 0.f, 0.f, 0.f};
#pragma unroll
        for (int kc = 0; kc < 4; kc++) {
            f16x8 a = *(const f16x8*)&As[((kc * 4 + w) * 64 + lane) * 8];
#pragma unroll
            for (int ct = 0; ct < NCT; ct++) {
                f16x8 b = *(const f16x8*)&Bs[((kc * NCT + ct) * 64 + lane) * 8];
                acc[ct] = __builtin_amdgcn_mfma_f32_16x16x32_f16(a, b, acc[ct], 0, 0, 0);
            }
        }

        // ---- epilogue via LDS bounce (inv precomputed by deg_inv_kernel) ----
        __syncthreads();
        ushort16* Ds = (ushort16*)As;      // [64][C]
        const int q = lane >> 4;
        float iv[4];
#pragma unroll
        for (int reg = 0; reg < 4; reg++) {
            int row = row0 + w * 16 + q * 4 + reg;
            iv[reg] = (row < N) ? inv[row] : 0.f;
        }
#pragma unroll
        for (int ct = 0; ct < NCT; ct++) {
#pragma unroll
            for (int reg = 0; reg < 4; reg++) {
                int r = w * 16 + q * 4 + reg;
                Ds[r * C + ct * 16 + (lane & 15)] = f2bf(acc[ct][reg] * iv[reg]);
            }
        }
        __syncthreads();
        {
            int r  = tid >> 2;
            int row = row0 + r;
            if (row < N) {
                constexpr int SPT = C / 4;
                int c0 = (tid & 3) * SPT;
                const uint4* s = (const uint4*)&Ds[r * C + c0];
                uint4* d = (uint4*)(outb + (size_t)row * C + c0);
#pragma unroll
                for (int i = 0; i < SPT / 8; i++) d[i] = s[i];
            }
        }
    }
}

// ---------------- FUSED: gather-agg layer 1 (relu) -> LDS A-fragments -> GEMM2 ----------------
// R2-proven 69us/48-VGPR structure, row-major bf16 hs2 epilogue (R6 config).
// Fused gather is at its compulsory-miss floor: FETCH 188MB ~ 8 XCD x 25.6MB
// working-set replication, served at ~2.7 TB/s. Concurrency (R0-R2), SW
// pipelining (R3), coalescing remap (R5), XCD slicing (R7) all null/negative.

__launch_bounds__(512, 4)
__global__ void fused_gather_gemm(const int* __restrict__ rowbeg, const int* __restrict__ rowend,
                                  const int* __restrict__ csr,
                                  const ushort16* __restrict__ hsb,    // [N][128] bf16
                                  const float* __restrict__ inv, const float* __restrict__ bias1,
                                  const f16* __restrict__ Wf2,         // B-frag, K=128, C=64
                                  ushort16* __restrict__ outb, int N) {  // [N][64] bf16
    constexpr int CIN = 128, COUT = 64, NCT = COUT / 16;    // NCT=4
    __shared__ __align__(16) f16 As[4 * 4 * 64 * 8];        // 16 KB
    __shared__ __align__(16) f16 Bs[4 * NCT * 64 * 8];      // 16 KB

    const int tid  = threadIdx.x;
    const int lane = tid & 63;
    const int w    = tid >> 6;          // 0..7
    const int row0 = blockIdx.x * 64;

    // ---- stage Wf2 -> Bs (1024 uint4, 512 threads x 2) ----
    {
        const uint4* s = (const uint4*)Wf2;
        uint4* d = (uint4*)Bs;
        d[tid]       = s[tid];
        d[tid + 512] = s[tid + 512];
    }

    // ---- gather phase (channel-split eighths) ----
    {
        const int r = tid >> 3;         // node 0..63
        const int q = tid & 7;          // channel eighth
        const int n = row0 + r;
        float acc[16];
#pragma unroll
        for (int j = 0; j < 16; j++) acc[j] = 0.f;

        if (n < N) {
            {   // self-loop row
                const ushort16* base = hsb + (size_t)n * CIN + q * 16;
                uint4 s0 = *(const uint4*)(base);
                uint4 s1 = *(const uint4*)(base + 8);
                acc_row(s0, acc); acc_row(s1, acc + 8);
            }
            const int end = rowend[n];
            int i = rowbeg[n];
            for (; i + 4 <= end; i += 4) {    // 4-edge unroll -> 8 outstanding 16B loads
                const ushort16* p0 = hsb + (size_t)csr[i]     * CIN + q * 16;
                const ushort16* p1 = hsb + (size_t)csr[i + 1] * CIN + q * 16;
                const ushort16* p2 = hsb + (size_t)csr[i + 2] * CIN + q * 16;
                const ushort16* p3 = hsb + (size_t)csr[i + 3] * CIN + q * 16;
                uint4 a0 = *(const uint4*)(p0);
                uint4 a1 = *(const uint4*)(p0 + 8);
                uint4 b0 = *(const uint4*)(p1);
                uint4 b1 = *(const uint4*)(p1 + 8);
                uint4 c0 = *(const uint4*)(p2);
                uint4 c1 = *(const uint4*)(p2 + 8);
                uint4 d0 = *(const uint4*)(p3);
                uint4 d1 = *(const uint4*)(p3 + 8);
                acc_row(a0, acc); acc_row(a1, acc + 8);
                acc_row(b0, acc); acc_row(b1, acc + 8);
                acc_row(c0, acc); acc_row(c1, acc + 8);
                acc_row(d0, acc); acc_row(d1, acc + 8);
            }
            for (; i < end; i++) {
                const ushort16* p0 = hsb + (size_t)csr[i] * CIN + q * 16;
                uint4 a0 = *(const uint4*)(p0);
                uint4 a1 = *(const uint4*)(p0 + 8);
                acc_row(a0, acc); acc_row(a1, acc + 8);
            }

            float iv = inv[n];
#pragma unroll
            for (int j = 0; j < 16; j++)
                acc[j] = fmaxf(fmaf(iv, acc[j], bias1[q * 16 + j]), 0.f);
        }

        // write h1 (f16) into As in A-fragment layout: channel k = q*16 + u*8 + j
        const int ws_ = r >> 4, r15 = r & 15;
        const int seg = q >> 1;
#pragma unroll
        for (int u = 0; u < 2; u++) {
            const int i8 = (q & 1) * 2 + u;
            f16 hv[8];
#pragma unroll
            for (int j = 0; j < 8; j++) hv[j] = (f16)acc[u * 8 + j];
            int slot = ((seg * 4 + ws_) * 64 + (i8 * 16 + r15)) * 8;
            *(uint4*)(As + slot) = *(const uint4*)hv;
        }
    }
    __syncthreads();

    // ---- MFMA: hs2 = inv * (h1 @ W2), waves 0-3 only ----
    f32x4 acc2[NCT];
#pragma unroll
    for (int c = 0; c < NCT; c++) acc2[c] = (f32x4){0.f, 0.f, 0.f, 0.f};
    if (w < 4) {
#pragma unroll
        for (int kc = 0; kc < 4; kc++) {
            f16x8 a = *(const f16x8*)&As[((kc * 4 + w) * 64 + lane) * 8];
#pragma unroll
            for (int ct = 0; ct < NCT; ct++) {
                f16x8 b = *(const f16x8*)&Bs[((kc * NCT + ct) * 64 + lane) * 8];
                acc2[ct] = __builtin_amdgcn_mfma_f32_16x16x32_f16(a, b, acc2[ct], 0, 0, 0);
            }
        }
    }

    // ---- epilogue via LDS bounce (reuse As) ----
    __syncthreads();
    ushort16* Ds = (ushort16*)As;      // [64][COUT]
    if (w < 4) {
        const int q2 = lane >> 4;
        float iv2[4];
#pragma unroll
        for (int reg = 0; reg < 4; reg++) {
            int row = row0 + w * 16 + q2 * 4 + reg;
            iv2[reg] = (row < N) ? inv[row] : 0.f;
        }
#pragma unroll
        for (int ct = 0; ct < NCT; ct++) {
#pragma unroll
            for (int reg = 0; reg < 4; reg++) {
                int r = w * 16 + q2 * 4 + reg;
                Ds[r * COUT + ct * 16 + (lane & 15)] = f2bf(acc2[ct][reg] * iv2[reg]);
            }
        }
    }
    __syncthreads();
    {
        const int r   = tid >> 3;          // 64 rows x 8 threads
        const int row = row0 + r;
        if (row < N) {
            const int c0 = (tid & 7) * 8;  // 16 B per thread
            *(uint4*)(outb + (size_t)row * COUT + c0) = *(const uint4*)&Ds[r * COUT + c0];
        }
    }
}

// ---------------- final gather (layer 2): row-major, fp32 out (R2 geometry) ----------------

template <int C, bool RELU>
__launch_bounds__(256)
__global__ void gather_agg_bf16(const int* __restrict__ rowbeg, const int* __restrict__ rowend,
                                const int* __restrict__ csr_src,
                                const ushort16* __restrict__ hsb, const float* __restrict__ inv,
                                const float* __restrict__ b, float* __restrict__ out, int N) {
    constexpr int TPN = C / 8;
    constexpr int NPB = 256 / TPN;
    int n    = blockIdx.x * NPB + threadIdx.x / TPN;
    int lane = threadIdx.x % TPN;
    if (n >= N) return;
    int c8 = lane * 8;

    float acc[8];
    {
        uint4 raw = *(const uint4*)(hsb + (size_t)n * C + c8);
        unpack2(raw.x, acc[0], acc[1]);
        unpack2(raw.y, acc[2], acc[3]);
        unpack2(raw.z, acc[4], acc[5]);
        unpack2(raw.w, acc[6], acc[7]);
    }

    int beg = rowbeg[n];
    int end = rowend[n];
    int i = beg;
    for (; i + 4 <= end; i += 4) {
        int s0 = csr_src[i];
        int s1 = csr_src[i + 1];
        int s2 = csr_src[i + 2];
        int s3 = csr_src[i + 3];
        uint4 r0 = *(const uint4*)(hsb + (size_t)s0 * C + c8);
        uint4 r1 = *(const uint4*)(hsb + (size_t)s1 * C + c8);
        uint4 r2 = *(const uint4*)(hsb + (size_t)s2 * C + c8);
        uint4 r3 = *(const uint4*)(hsb + (size_t)s3 * C + c8);
        acc_row(r0, acc); acc_row(r1, acc); acc_row(r2, acc); acc_row(r3, acc);
    }
    for (; i < end; i++) {
        uint4 r0 = *(const uint4*)(hsb + (size_t)csr_src[i] * C + c8);
        acc_row(r0, acc);
    }

    float iv = inv[n];
    float4 b0 = *(const float4*)(b + c8);
    float4 b1 = *(const float4*)(b + c8 + 4);
    float r[8];
    r[0] = fmaf(iv, acc[0], b0.x); r[1] = fmaf(iv, acc[1], b0.y);
    r[2] = fmaf(iv, acc[2], b0.z); r[3] = fmaf(iv, acc[3], b0.w);
    r[4] = fmaf(iv, acc[4], b1.x); r[5] = fmaf(iv, acc[5], b1.y);
    r[6] = fmaf(iv, acc[6], b1.z); r[7] = fmaf(iv, acc[7], b1.w);
    if (RELU) {
#pragma unroll
        for (int j = 0; j < 8; j++) r[j] = fmaxf(r[j], 0.f);
    }
    float* po = out + (size_t)n * C + c8;
    *(float4*)(po)     = make_float4(r[0], r[1], r[2], r[3]);
    *(float4*)(po + 4) = make_float4(r[4], r[5], r[6], r[7]);
}

extern "C" void kernel_launch(void* const* d_in, const int* in_sizes, int n_in,
                              void* d_out, int out_size, void* d_ws, size_t ws_size,
                              hipStream_t stream) {
    const float* x  = (const float*)d_in[0];
    const int*   ei = (const int*)d_in[1];
    const float* W1 = (const float*)d_in[2];
    const float* b1 = (const float*)d_in[3];
    const float* W2 = (const float*)d_in[4];
    const float* b2 = (const float*)d_in[5];
    float* out = (float*)d_out;

    const int N = in_sizes[0] / IN_C;    // 100000 (<= 131072 for src packing)
    const int E = in_sizes[1] / 2;       // 1600000
    const int* src = ei;
    const int* dst = ei + E;
    const int nbuck = (N + BSPAN - 1) / BSPAN;   // 391
    const int nbins = (E + ACHUNK - 1) / ACHUNK; // 391

    // workspace layout
    char* ws = (char*)d_ws;
    auto align_up = [](size_t v) { return (v + 1023) & ~(size_t)1023; };
    size_t off = 0;
    int*      bucketCur = (int*)(ws + off);      off += align_up((size_t)nbuck * sizeof(int));
    float*    inv       = (float*)(ws + off);    off += align_up((size_t)N * sizeof(float));
    int*      rowbeg    = (int*)(ws + off);      off += align_up((size_t)N * sizeof(int));
    int*      rowend    = (int*)(ws + off);      off += align_up((size_t)N * sizeof(int));
    uint32*   binned    = (uint32*)(ws + off);   off += align_up((size_t)nbuck * BCAP * sizeof(uint32));
    int*      csrs      = (int*)(ws + off);      off += align_up((size_t)nbuck * BCAP * sizeof(int));
    f16*      Wf1       = (f16*)(ws + off);      off += align_up((size_t)4 * (HID_C/16) * 64 * 8 * sizeof(f16));
    f16*      Wf2       = (f16*)(ws + off);      off += align_up((size_t)4 * (OUT_C/16) * 64 * 8 * sizeof(f16));
    ushort16* hs1b      = (ushort16*)(ws + off); off += align_up((size_t)N * HID_C * sizeof(ushort16));
    ushort16* hs2b      = (ushort16*)(ws + off); off += align_up((size_t)N * OUT_C * sizeof(ushort16));

    // ---- zero bucketCur (replaces wprep's zeroing) ----
    hipMemsetAsync(bucketCur, 0, (size_t)nbuck * sizeof(int), stream);

    // ---- MERGED: binning (391 blocks) || weight swizzle (12 blocks) ----
    {
        constexpr int WPT = 4 * (HID_C / 16 + OUT_C / 16) * 64;   // 3072 threads
        bin_edges_wprep<<<nbins + (WPT + 255) / 256, 256, 0, stream>>>(
            src, dst, bucketCur, binned, W1, Wf1, W2, Wf2, E, nbins);
    }

    // ---- per-node degree -> inv (bucket recount, no global atomics) ----
    deg_inv_kernel<<<nbuck, 256, 0, stream>>>(binned, bucketCur, inv, N);

    // ---- MERGED: bucket CSR (391 blocks) || layer-1 GEMM (1563 blocks) ----
    {
        const int ngemm = (N + 63) / 64;
        csr_and_gemm<<<nbuck + ngemm, 256, 0, stream>>>(
            binned, bucketCur, csrs, rowbeg, rowend,
            x, Wf1, inv, hs1b, N, nbuck);
    }

    // ---- fused: gather1 + relu + GEMM2 (512 threads: 8 thr/node, channel-split) ----
    fused_gather_gemm<<<(N + 63) / 64, 512, 0, stream>>>(
        rowbeg, rowend, csrs, hs1b, inv, b1, Wf2, hs2b, N);

    // ---- final gather ----
    {
        constexpr int NPB = 256 / (OUT_C / 8);
        gather_agg_bf16<OUT_C, false><<<(N + NPB - 1) / NPB, 256, 0, stream>>>(
            rowbeg, rowend, csrs, hs2b, inv, b2, out, N);
    }
}